// Round 5
// baseline (85.091 us; speedup 1.0000x reference)
//
#include <hip/hip_runtime.h>
#include <math.h>

#define NPRED 16384
#define NGT   32768
#define BETA  0.45f
#define GAMMA 0.45f

#define BLOCK 256
#define PPT   8                                // preds per thread
#define PRED_PER_BLOCK (BLOCK * PPT)           // 2048
#define PRED_CHUNKS (NPRED / PRED_PER_BLOCK)   // 8
#define SLAB  256                              // gt rows per block (== BLOCK)
#define NSLAB (NGT / SLAB)                     // 128

// ---------------------------------------------------------------------------
// nn: min-distance only (no index in the hot loop).
//   LDS h = (-2gx,-2gy,-2gz,|g|^2);  d = fma(px,hx,fma(py,hy,fma(pz,hz,hw)))
//   reduce: v_min3_f32(kmin, d0, d1)  -> 3.5 VALU ops/pair, exact fp32.
// Cross-slab merge: u64 atomicMin on sortable(dmin) << 32 | slab_id
//   (ties -> lower slab; rescan takes first j -> global first occurrence).
// chunk==0 blocks also write h to global for the rescan pass.
// Ping-pong LDS prefetch (rows j+2,j+3 load while j,j+1 compute).
// ---------------------------------------------------------------------------
__global__ __launch_bounds__(BLOCK) void nn_kernel(
    const float* __restrict__ pred_feat,
    const float* __restrict__ gt_data,
    unsigned long long* __restrict__ packed,
    float4* __restrict__ hglob)
{
    __shared__ float4 hs[SLAB + 2];

    const int chunk   = blockIdx.x;
    const int slab    = blockIdx.y;
    const int gt_base = slab * SLAB;
    const int t       = threadIdx.x;

    {
        const int gj = gt_base + t;
        const float x = gt_data[gj * 6 + 0];
        const float y = gt_data[gj * 6 + 1];
        const float z = gt_data[gj * 6 + 2];
        const float4 h = make_float4(-2.0f * x, -2.0f * y, -2.0f * z,
                                     fmaf(x, x, fmaf(y, y, z * z)));
        hs[t] = h;
        if (chunk == 0) hglob[gj] = h;
        if (t < 2) hs[SLAB + t] = make_float4(0.0f, 0.0f, 0.0f, 1e30f); // pad
    }
    __syncthreads();

    float px[PPT], py[PPT], pz[PPT], kmin[PPT];
    const int pred_base = chunk * PRED_PER_BLOCK + t;
#pragma unroll
    for (int p = 0; p < PPT; ++p) {
        const int i = pred_base + p * BLOCK;
        px[p] = pred_feat[i * 6 + 0];
        py[p] = pred_feat[i * 6 + 1];
        pz[p] = pred_feat[i * 6 + 2];
        kmin[p] = 1e30f;
    }

#define STEP(G0, G1)                                                          \
    _Pragma("unroll")                                                         \
    for (int p = 0; p < PPT; ++p) {                                           \
        const float d0 = fmaf(px[p], G0.x, fmaf(py[p], G0.y,                  \
                              fmaf(pz[p], G0.z, G0.w)));                      \
        const float d1 = fmaf(px[p], G1.x, fmaf(py[p], G1.y,                  \
                              fmaf(pz[p], G1.z, G1.w)));                      \
        asm("v_min3_f32 %0, %0, %1, %2" : "+v"(kmin[p]) : "v"(d0), "v"(d1));  \
    }

    float4 a0 = hs[0], a1 = hs[1], b0, b1;
#pragma unroll 1
    for (int j = 0; j < SLAB; j += 4) {
        b0 = hs[j + 2]; b1 = hs[j + 3];
        STEP(a0, a1)
        a0 = hs[j + 4]; a1 = hs[j + 5];   // last iter reads pad rows (unused)
        STEP(b0, b1)
    }
#undef STEP

#pragma unroll
    for (int p = 0; p < PPT; ++p) {
        const int i = pred_base + p * BLOCK;
        const unsigned int bits = __float_as_uint(kmin[p]);
        const unsigned int key  = (bits & 0x80000000u) ? ~bits : (bits | 0x80000000u);
        const unsigned long long pk =
            ((unsigned long long)key << 32) | (unsigned int)slab;
        atomicMin(&packed[i], pk);
    }
}

// ---------------------------------------------------------------------------
// rescan + finalize: recover argmin index by re-scanning the winning slab
// with the bit-identical fmaf chain, then normals cosine + regularizer.
// ---------------------------------------------------------------------------
__global__ __launch_bounds__(BLOCK) void rescan_kernel(
    const float* __restrict__ pred_feat,
    const float* __restrict__ gt_data,
    const float4* __restrict__ hglob,
    const float* __restrict__ Rm,
    const float* __restrict__ tv,
    const float* __restrict__ sv,
    const unsigned long long* __restrict__ packed,
    float* __restrict__ out)
{
    const int i = blockIdx.x * BLOCK + threadIdx.x;

    const unsigned long long pk = packed[i];
    const unsigned int key  = (unsigned int)(pk >> 32);
    const unsigned int slab = (unsigned int)(pk & 0xFFFFFFFFu);
    // inverse of the sortable transform
    const unsigned int tbits = (key & 0x80000000u) ? (key ^ 0x80000000u) : ~key;
    const int gt_base = slab * SLAB;

    const float px = pred_feat[i * 6 + 0];
    const float py = pred_feat[i * 6 + 1];
    const float pz = pred_feat[i * 6 + 2];

    int jw = SLAB;
#pragma unroll 4
    for (int j = 0; j < SLAB; ++j) {
        const float4 g = hglob[gt_base + j];
        const float d = fmaf(px, g.x, fmaf(py, g.y, fmaf(pz, g.z, g.w)));
        if (__float_as_uint(d) == tbits) jw = min(jw, j);
    }
    const int idx = gt_base + ((jw < SLAB) ? jw : 0);

    const float nx = pred_feat[i * 6 + 3];
    const float ny = pred_feat[i * 6 + 4];
    const float nz = pred_feat[i * 6 + 5];
    const float gx = gt_data[idx * 6 + 3];
    const float gy = gt_data[idx * 6 + 4];
    const float gz = gt_data[idx * 6 + 5];
    const float pn = fmaxf(sqrtf(fmaf(nx, nx, fmaf(ny, ny, nz * nz))), 1e-12f);
    const float gn = fmaxf(sqrtf(fmaf(gx, gx, fmaf(gy, gy, gz * gz))), 1e-12f);
    const float cosv = fmaf(nx, gx, fmaf(ny, gy, nz * gz)) / (pn * gn);
    float c = 1.0f - cosv;

#pragma unroll
    for (int off = 32; off > 0; off >>= 1) c += __shfl_down(c, off, 64);
    if ((threadIdx.x & 63) == 0) atomicAdd(out, c * (GAMMA / (float)NPRED));

    if (blockIdx.x == 0 && threadIdx.x == 0) {
        float rs = 0.0f;
#pragma unroll
        for (int k = 0; k < 9; ++k) {
            const float v = Rm[k] - ((k % 4 == 0) ? 1.0f : 0.0f);
            rs = fmaf(v, v, rs);
        }
        const float rot = sqrtf(rs);
        const float tr  = sqrtf(fmaf(tv[0], tv[0], fmaf(tv[1], tv[1], tv[2] * tv[2])));
        const float sc  = (sv[0] - 1.0f) * (sv[0] - 1.0f);
        atomicAdd(out, BETA * (rot + tr + sc));
    }
}

extern "C" void kernel_launch(void* const* d_in, const int* in_sizes, int n_in,
                              void* d_out, int out_size, void* d_ws, size_t ws_size,
                              hipStream_t stream)
{
    const float* pred = (const float*)d_in[0];
    const float* gt   = (const float*)d_in[1];
    const float* Rm   = (const float*)d_in[2];
    const float* tv   = (const float*)d_in[3];
    const float* sv   = (const float*)d_in[4];
    float* out = (float*)d_out;

    unsigned long long* packed = (unsigned long long*)d_ws;                    // 128 KB
    float4* hglob = (float4*)((char*)d_ws + NPRED * sizeof(unsigned long long)); // 512 KB

    hipMemsetAsync(packed, 0xFF, NPRED * sizeof(unsigned long long), stream);
    hipMemsetAsync(out, 0, sizeof(float), stream);

    dim3 grid(PRED_CHUNKS, NSLAB);
    nn_kernel<<<grid, BLOCK, 0, stream>>>(pred, gt, packed, hglob);
    rescan_kernel<<<NPRED / BLOCK, BLOCK, 0, stream>>>(pred, gt, hglob, Rm, tv, sv,
                                                       packed, out);
}

// Round 6
// 72.933 us; speedup vs baseline: 1.1667x; 1.1667x over previous
//
#include <hip/hip_runtime.h>
#include <math.h>

#define NPRED 16384
#define NGT   32768
#define BETA  0.45f
#define GAMMA 0.45f

#define BLOCK 256
#define PPT   16                               // preds per thread
#define PRED_PER_BLOCK (BLOCK * PPT)           // 4096
#define PRED_CHUNKS (NPRED / PRED_PER_BLOCK)   // 4
#define SLAB  256                              // gt rows per block (== BLOCK)
#define NSLAB (NGT / SLAB)                     // 128

// ---------------------------------------------------------------------------
// nn: min-distance only (no index in the hot loop), 3.5 VALU ops/pair.
//   LDS h = (-2gx,-2gy,-2gz,|g|^2);  d = fma(px,hx,fma(py,hy,fma(pz,hz,hw)))
//   reduce: v_min3_f32(kmin, d0, d1). PPT=16 so the LDS broadcast read is
//   amortized over 112 VALU ops/row (LDS pipe ~43% vs ~86% at PPT=8).
// Cross-slab merge: u64 atomicMin on sortable(dmin) << 32 | slab_id
//   (ties -> lower slab = smaller global index; rescan takes first j).
// ---------------------------------------------------------------------------
__global__ __launch_bounds__(BLOCK) void nn_kernel(
    const float* __restrict__ pred_feat,
    const float* __restrict__ gt_data,
    unsigned long long* __restrict__ packed,
    float4* __restrict__ hglob)
{
    __shared__ float4 hs[SLAB + 2];

    const int chunk   = blockIdx.x;
    const int slab    = blockIdx.y;
    const int gt_base = slab * SLAB;
    const int t       = threadIdx.x;

    {
        const int gj = gt_base + t;
        const float x = gt_data[gj * 6 + 0];
        const float y = gt_data[gj * 6 + 1];
        const float z = gt_data[gj * 6 + 2];
        const float4 h = make_float4(-2.0f * x, -2.0f * y, -2.0f * z,
                                     fmaf(x, x, fmaf(y, y, z * z)));
        hs[t] = h;
        if (chunk == 0) hglob[gj] = h;
        if (t < 2) hs[SLAB + t] = make_float4(0.0f, 0.0f, 0.0f, 1e30f); // pad
    }
    __syncthreads();

    float px[PPT], py[PPT], pz[PPT], kmin[PPT];
    const int pred_base = chunk * PRED_PER_BLOCK + t;
#pragma unroll
    for (int p = 0; p < PPT; ++p) {
        const int i = pred_base + p * BLOCK;
        px[p] = pred_feat[i * 6 + 0];
        py[p] = pred_feat[i * 6 + 1];
        pz[p] = pred_feat[i * 6 + 2];
        kmin[p] = 1e30f;
    }

#define STEP(G0, G1)                                                          \
    _Pragma("unroll")                                                         \
    for (int p = 0; p < PPT; ++p) {                                           \
        const float d0 = fmaf(px[p], G0.x, fmaf(py[p], G0.y,                  \
                              fmaf(pz[p], G0.z, G0.w)));                      \
        const float d1 = fmaf(px[p], G1.x, fmaf(py[p], G1.y,                  \
                              fmaf(pz[p], G1.z, G1.w)));                      \
        asm("v_min3_f32 %0, %0, %1, %2" : "+v"(kmin[p]) : "v"(d0), "v"(d1));  \
    }

    float4 a0 = hs[0], a1 = hs[1], b0, b1;
#pragma unroll 1
    for (int j = 0; j < SLAB; j += 4) {
        b0 = hs[j + 2]; b1 = hs[j + 3];
        STEP(a0, a1)
        a0 = hs[j + 4]; a1 = hs[j + 5];   // last iter reads pad rows (unused)
        STEP(b0, b1)
    }
#undef STEP

#pragma unroll
    for (int p = 0; p < PPT; ++p) {
        const int i = pred_base + p * BLOCK;
        const unsigned int bits = __float_as_uint(kmin[p]);
        const unsigned int key  = (bits & 0x80000000u) ? ~bits : (bits | 0x80000000u);
        const unsigned long long pk =
            ((unsigned long long)key << 32) | (unsigned int)slab;
        atomicMin(&packed[i], pk);
    }
}

// ---------------------------------------------------------------------------
// rescan + finalize, wave-cooperative: one wave scans one pred's winning slab
// (lanes read rows k*64+lane -> coalesced; hglob is L2-resident). First match
// in ascending k via ballot+ffsll = first-j semantics. Each wave handles 4
// preds; one atomicAdd per block.
// ---------------------------------------------------------------------------
#define RES_PREDS_PER_WAVE 4
#define RES_PREDS_PER_BLOCK (4 * RES_PREDS_PER_WAVE)   // 4 waves/block -> 16
#define RES_BLOCKS (NPRED / RES_PREDS_PER_BLOCK)       // 1024

__global__ __launch_bounds__(BLOCK) void rescan_kernel(
    const float* __restrict__ pred_feat,
    const float* __restrict__ gt_data,
    const float4* __restrict__ hglob,
    const float* __restrict__ Rm,
    const float* __restrict__ tv,
    const float* __restrict__ sv,
    const unsigned long long* __restrict__ packed,
    float* __restrict__ out)
{
    __shared__ float wsum[4];
    const int wave = threadIdx.x >> 6;
    const int lane = threadIdx.x & 63;

    float csum = 0.0f;
#pragma unroll
    for (int q = 0; q < RES_PREDS_PER_WAVE; ++q) {
        const int i = blockIdx.x * RES_PREDS_PER_BLOCK + wave * RES_PREDS_PER_WAVE + q;

        const unsigned long long pk = packed[i];
        const unsigned int key  = (unsigned int)(pk >> 32);
        const unsigned int slab = (unsigned int)(pk & 0xFFFFFFFFu);
        const unsigned int tbits = (key & 0x80000000u) ? (key ^ 0x80000000u) : ~key;
        const int gt_base = (int)slab * SLAB;

        const float px = pred_feat[i * 6 + 0];
        const float py = pred_feat[i * 6 + 1];
        const float pz = pred_feat[i * 6 + 2];

        int jfound = 0;
        bool done = false;
#pragma unroll
        for (int k = 0; k < SLAB / 64; ++k) {
            const float4 g = hglob[gt_base + k * 64 + lane];
            const float d = fmaf(px, g.x, fmaf(py, g.y, fmaf(pz, g.z, g.w)));
            const unsigned long long m = __ballot(__float_as_uint(d) == tbits);
            if (!done && m) {
                jfound = k * 64 + (__ffsll((unsigned long long)m) - 1);
                done = true;
            }
        }
        const int idx = gt_base + jfound;

        if (lane == 0) {
            const float nx = pred_feat[i * 6 + 3];
            const float ny = pred_feat[i * 6 + 4];
            const float nz = pred_feat[i * 6 + 5];
            const float gx = gt_data[idx * 6 + 3];
            const float gy = gt_data[idx * 6 + 4];
            const float gz = gt_data[idx * 6 + 5];
            const float pn = fmaxf(sqrtf(fmaf(nx, nx, fmaf(ny, ny, nz * nz))), 1e-12f);
            const float gn = fmaxf(sqrtf(fmaf(gx, gx, fmaf(gy, gy, gz * gz))), 1e-12f);
            const float cosv = fmaf(nx, gx, fmaf(ny, gy, nz * gz)) / (pn * gn);
            csum += 1.0f - cosv;
        }
    }

    if (lane == 0) wsum[wave] = csum;
    __syncthreads();

    if (threadIdx.x == 0) {
        float s = wsum[0] + wsum[1] + wsum[2] + wsum[3];
        atomicAdd(out, s * (GAMMA / (float)NPRED));
        if (blockIdx.x == 0) {
            float rs = 0.0f;
#pragma unroll
            for (int k = 0; k < 9; ++k) {
                const float v = Rm[k] - ((k % 4 == 0) ? 1.0f : 0.0f);
                rs = fmaf(v, v, rs);
            }
            const float rot = sqrtf(rs);
            const float tr  = sqrtf(fmaf(tv[0], tv[0], fmaf(tv[1], tv[1], tv[2] * tv[2])));
            const float sc  = (sv[0] - 1.0f) * (sv[0] - 1.0f);
            atomicAdd(out, BETA * (rot + tr + sc));
        }
    }
}

extern "C" void kernel_launch(void* const* d_in, const int* in_sizes, int n_in,
                              void* d_out, int out_size, void* d_ws, size_t ws_size,
                              hipStream_t stream)
{
    const float* pred = (const float*)d_in[0];
    const float* gt   = (const float*)d_in[1];
    const float* Rm   = (const float*)d_in[2];
    const float* tv   = (const float*)d_in[3];
    const float* sv   = (const float*)d_in[4];
    float* out = (float*)d_out;

    unsigned long long* packed = (unsigned long long*)d_ws;                      // 128 KB
    float4* hglob = (float4*)((char*)d_ws + NPRED * sizeof(unsigned long long)); // 512 KB

    hipMemsetAsync(packed, 0xFF, NPRED * sizeof(unsigned long long), stream);
    hipMemsetAsync(out, 0, sizeof(float), stream);

    dim3 grid(PRED_CHUNKS, NSLAB);
    nn_kernel<<<grid, BLOCK, 0, stream>>>(pred, gt, packed, hglob);
    rescan_kernel<<<RES_BLOCKS, BLOCK, 0, stream>>>(pred, gt, hglob, Rm, tv, sv,
                                                    packed, out);
}